// Round 2
// baseline (461.006 us; speedup 1.0000x reference)
//
#include <hip/hip_runtime.h>
#include <hip/hip_bf16.h>

// GaussianPolicy: SNN-LIF frontend + 2-branch MLP heads.
// B=4096, IN=512, H=2048, A=32. fp32 in/out; bf16 MFMA compute internally.
// fc GEMM uses hi/lo bf16 split (3 MFMA products) so LIF spike decisions
// match the fp32 reference; MLP GEMMs are plain bf16 (2% tolerance).

typedef __hip_bfloat16 bf16;
using f32x4 = __attribute__((ext_vector_type(4))) float;
using s16x8 = __attribute__((ext_vector_type(8))) short;   // 8 bf16 in 4 VGPRs

#define MFMA16(a, b, c) __builtin_amdgcn_mfma_f32_16x16x32_bf16((a), (b), (c), 0, 0, 0)

__device__ __forceinline__ void gload16(const void* g, void* l) {
  __builtin_amdgcn_global_load_lds(
      (const __attribute__((address_space(1))) unsigned int*)g,
      (__attribute__((address_space(3))) unsigned int*)l, 16, 0, 0);
}

// ---------------------------------------------------------------------------
// fp32 -> (hi, lo) bf16 split.  hi = bf16(x), lo = bf16(x - hi).
// ---------------------------------------------------------------------------
__global__ __launch_bounds__(256) void split_kernel(
    const float* __restrict__ src, bf16* __restrict__ hi, bf16* __restrict__ lo, int n8)
{
  int i = blockIdx.x * 256 + threadIdx.x;
  if (i >= n8) return;
  const float4* s4 = (const float4*)src;
  float4 a = s4[(size_t)i * 2], b = s4[(size_t)i * 2 + 1];
  float v[8] = {a.x, a.y, a.z, a.w, b.x, b.y, b.z, b.w};
  bf16 h[8], l[8];
#pragma unroll
  for (int j = 0; j < 8; ++j) {
    h[j] = __float2bfloat16(v[j]);
    l[j] = __float2bfloat16(v[j] - __bfloat162float(h[j]));
  }
  *(s16x8*)(hi + (size_t)i * 8) = *(const s16x8*)h;
  *(s16x8*)(lo + (size_t)i * 8) = *(const s16x8*)l;
}

// fp32 -> bf16
__global__ __launch_bounds__(256) void cvt_kernel(
    const float* __restrict__ src, bf16* __restrict__ dst, int n8)
{
  int i = blockIdx.x * 256 + threadIdx.x;
  if (i >= n8) return;
  const float4* s4 = (const float4*)src;
  float4 a = s4[(size_t)i * 2], b = s4[(size_t)i * 2 + 1];
  float v[8] = {a.x, a.y, a.z, a.w, b.x, b.y, b.z, b.w};
  bf16 d[8];
#pragma unroll
  for (int j = 0; j < 8; ++j) d[j] = __float2bfloat16(v[j]);
  *(s16x8*)(dst + (size_t)i * 8) = *(const s16x8*)d;
}

// ---------------------------------------------------------------------------
// LIF kernel: fc[b,s,h] = state_s @ W_lif^T via split bf16 (hi*hi+hi*lo+lo*hi),
// then 15-step LIF recurrence, x = spike-mean.  Tile 128x128, 8 waves (2x4),
// wave = 64x32, 5 slice accumulators; s-outer loop over full K=512.
// ---------------------------------------------------------------------------
__global__ __launch_bounds__(512) void lif_kernel(
    const bf16* __restrict__ Sh, const bf16* __restrict__ Sl,
    const bf16* __restrict__ Wh, const bf16* __restrict__ Wlo,
    const float* __restrict__ bl, bf16* __restrict__ X)
{
  const int K = 512, N = 2048;
  __shared__ alignas(16) bf16 Ah[2][128 * 32];
  __shared__ alignas(16) bf16 Al[2][128 * 32];
  __shared__ alignas(16) bf16 Bh[2][128 * 32];
  __shared__ alignas(16) bf16 Bl[2][128 * 32];

  const int tid = threadIdx.x, wid = tid >> 6, lane = tid & 63;
  const int b0 = (blockIdx.x >> 4) * 128;   // 4096/128 = 32
  const int h0 = (blockIdx.x & 15) * 128;   // 2048/128 = 16
  const int wr = (wid >> 2) * 64, wc = (wid & 3) * 32;
  const int srow = tid >> 2, skol = (tid & 3) * 8;
  const int kb = (lane >> 4) * 8, fr = lane & 15, fq = lane >> 4;

  f32x4 acc[5][4][2] = {};

  auto STAGE = [&](int p, int s, int k0) {
    gload16(Sh + ((size_t)(b0 + srow) * 5 + s) * K + k0 + skol, &Ah[p][tid * 8]);
    gload16(Sl + ((size_t)(b0 + srow) * 5 + s) * K + k0 + skol, &Al[p][tid * 8]);
    gload16(Wh + (size_t)(h0 + srow) * K + k0 + skol, &Bh[p][tid * 8]);
    gload16(Wlo + (size_t)(h0 + srow) * K + k0 + skol, &Bl[p][tid * 8]);
  };

#pragma unroll
  for (int s = 0; s < 5; ++s) {
    STAGE(0, s, 0);
    __syncthreads();
    int cur = 0;
    for (int kt = 0; kt < 16; ++kt) {
      if (kt + 1 < 16) STAGE(cur ^ 1, s, (kt + 1) * 32);
      s16x8 ah[4], al[4], bh[2], blo[2];
#pragma unroll
      for (int m = 0; m < 4; ++m) {
        ah[m] = *(const s16x8*)&Ah[cur][(wr + m * 16 + fr) * 32 + kb];
        al[m] = *(const s16x8*)&Al[cur][(wr + m * 16 + fr) * 32 + kb];
      }
#pragma unroll
      for (int n = 0; n < 2; ++n) {
        bh[n]  = *(const s16x8*)&Bh[cur][(wc + n * 16 + fr) * 32 + kb];
        blo[n] = *(const s16x8*)&Bl[cur][(wc + n * 16 + fr) * 32 + kb];
      }
#pragma unroll
      for (int m = 0; m < 4; ++m)
#pragma unroll
        for (int n = 0; n < 2; ++n) {
          acc[s][m][n] = MFMA16(ah[m], bh[n],  acc[s][m][n]);
          acc[s][m][n] = MFMA16(ah[m], blo[n], acc[s][m][n]);
          acc[s][m][n] = MFMA16(al[m], bh[n],  acc[s][m][n]);
        }
      __syncthreads();
      cur ^= 1;
    }
  }

  // LIF epilogue: 5 slices x3 steps; x = spike count / 15
#pragma unroll
  for (int m = 0; m < 4; ++m) {
#pragma unroll
    for (int n = 0; n < 2; ++n) {
      const int col = h0 + wc + n * 16 + fr;
      const float bv = bl[col];
#pragma unroll
      for (int r = 0; r < 4; ++r) {
        const int row = b0 + wr + m * 16 + fq * 4 + r;
        float mem = 0.f, spk = 0.f, cnt = 0.f;
#pragma unroll
        for (int s = 0; s < 5; ++s) {
          const float fc = acc[s][m][n][r] + bv;
#pragma unroll
          for (int j = 0; j < 3; ++j) {
            mem = mem * 0.2f * (1.f - spk) + fc;   // DECAY=0.2
            spk = (mem > 0.2f) ? 1.f : 0.f;        // THRESH=0.2
            cnt += spk;
          }
        }
        X[(size_t)row * N + col] = __float2bfloat16(cnt / 15.0f);
      }
    }
  }
}

// ---------------------------------------------------------------------------
// C = relu(A @ W^T + bias): A[M,K] bf16, W[N,K] bf16, bias fp32, C bf16.
// 128x128 tile, BK=32, 4 waves (2x2), wave 64x64 = 4x4 MFMA frags.
// ---------------------------------------------------------------------------
__global__ __launch_bounds__(256) void gemm_relu_kernel(
    const bf16* __restrict__ A, const bf16* __restrict__ W,
    const float* __restrict__ bias, bf16* __restrict__ C,
    int M, int N, int K)
{
  __shared__ alignas(16) bf16 As[2][128 * 32];
  __shared__ alignas(16) bf16 Bs[2][128 * 32];

  const int tid = threadIdx.x, wid = tid >> 6, lane = tid & 63;
  const int nbn = N / 128;
  const int bm0 = (blockIdx.x / nbn) * 128;
  const int bn0 = (blockIdx.x % nbn) * 128;
  const int wr = (wid >> 1) * 64, wc = (wid & 1) * 64;
  const int srow = tid >> 2, skol = (tid & 3) * 8;
  const int kb = (lane >> 4) * 8, fr = lane & 15, fq = lane >> 4;

  f32x4 acc[4][4] = {};

  auto STAGE = [&](int p, int k0) {
    gload16(A + (size_t)(bm0 + srow) * K + k0 + skol,      &As[p][tid * 8]);
    gload16(A + (size_t)(bm0 + 64 + srow) * K + k0 + skol, &As[p][2048 + tid * 8]);
    gload16(W + (size_t)(bn0 + srow) * K + k0 + skol,      &Bs[p][tid * 8]);
    gload16(W + (size_t)(bn0 + 64 + srow) * K + k0 + skol, &Bs[p][2048 + tid * 8]);
  };

  STAGE(0, 0);
  __syncthreads();
  int cur = 0;
  const int NT = K / 32;
  for (int kt = 0; kt < NT; ++kt) {
    if (kt + 1 < NT) STAGE(cur ^ 1, (kt + 1) * 32);
    s16x8 af[4], bf[4];
#pragma unroll
    for (int m = 0; m < 4; ++m)
      af[m] = *(const s16x8*)&As[cur][(wr + m * 16 + fr) * 32 + kb];
#pragma unroll
    for (int n = 0; n < 4; ++n)
      bf[n] = *(const s16x8*)&Bs[cur][(wc + n * 16 + fr) * 32 + kb];
#pragma unroll
    for (int m = 0; m < 4; ++m)
#pragma unroll
      for (int n = 0; n < 4; ++n)
        acc[m][n] = MFMA16(af[m], bf[n], acc[m][n]);
    __syncthreads();
    cur ^= 1;
  }

#pragma unroll
  for (int n = 0; n < 4; ++n) {
    const int col = bn0 + wc + n * 16 + fr;
    const float bv = bias[col];
#pragma unroll
    for (int m = 0; m < 4; ++m) {
      const int row0 = bm0 + wr + m * 16 + fq * 4;
#pragma unroll
      for (int r = 0; r < 4; ++r) {
        float v = fmaxf(acc[m][n][r] + bv, 0.f);
        C[(size_t)(row0 + r) * N + col] = __float2bfloat16(v);
      }
    }
  }
}

// ---------------------------------------------------------------------------
// Heads: mean = h12@Wm^T + bm ; log_std = clip(h22@Wls^T + bls, -20, 2).
// fp32 out. 4 waves x 16 rows per block, 2 col-frags (A=32).
// ---------------------------------------------------------------------------
__global__ __launch_bounds__(256) void head_kernel(
    const bf16* __restrict__ H1, const bf16* __restrict__ H2,
    const bf16* __restrict__ Wm, const float* __restrict__ bm,
    const bf16* __restrict__ Wls, const float* __restrict__ bls,
    float* __restrict__ OUT, int M, int K)
{
  const int tid = threadIdx.x, wid = tid >> 6, lane = tid & 63;
  const int m0 = blockIdx.x * 64 + wid * 16;
  const int kb = (lane >> 4) * 8, fr = lane & 15, fq = lane >> 4;

  f32x4 a1[2] = {}, a2[2] = {};
  for (int k0 = 0; k0 < K; k0 += 32) {
    s16x8 f1 = *(const s16x8*)&H1[(size_t)(m0 + fr) * K + k0 + kb];
    s16x8 f2 = *(const s16x8*)&H2[(size_t)(m0 + fr) * K + k0 + kb];
#pragma unroll
    for (int n = 0; n < 2; ++n) {
      s16x8 wm = *(const s16x8*)&Wm[(size_t)(n * 16 + fr) * K + k0 + kb];
      s16x8 wl = *(const s16x8*)&Wls[(size_t)(n * 16 + fr) * K + k0 + kb];
      a1[n] = MFMA16(f1, wm, a1[n]);
      a2[n] = MFMA16(f2, wl, a2[n]);
    }
  }

#pragma unroll
  for (int n = 0; n < 2; ++n) {
    const int col = n * 16 + fr;
    const float bvm = bm[col];
    const float bvl = bls[col];
#pragma unroll
    for (int r = 0; r < 4; ++r) {
      const int row = m0 + fq * 4 + r;
      OUT[(size_t)row * 32 + col] = a1[n][r] + bvm;
      float lv = a2[n][r] + bvl;
      OUT[(size_t)M * 32 + (size_t)row * 32 + col] = fminf(fmaxf(lv, -20.f), 2.f);
    }
  }
}

// ---------------------------------------------------------------------------
extern "C" void kernel_launch(void* const* d_in, const int* in_sizes, int n_in,
                              void* d_out, int out_size, void* d_ws, size_t ws_size,
                              hipStream_t stream) {
  const float* state = (const float*)d_in[0];
  const float* W_lif = (const float*)d_in[1];
  const float* b_lif = (const float*)d_in[2];
  const float* W11   = (const float*)d_in[3];
  const float* b11   = (const float*)d_in[4];
  const float* W12   = (const float*)d_in[5];
  const float* b12   = (const float*)d_in[6];
  const float* W21   = (const float*)d_in[7];
  const float* b21   = (const float*)d_in[8];
  const float* W22   = (const float*)d_in[9];
  const float* b22   = (const float*)d_in[10];
  const float* Wm    = (const float*)d_in[11];
  const float* bm    = (const float*)d_in[12];
  const float* Wls   = (const float*)d_in[13];
  const float* bls   = (const float*)d_in[14];
  float* out = (float*)d_out;

  const int B = 4096, IN = 512, H = 2048;
  const size_t SZ_X  = 16777216;   // B*H bf16 bytes
  const size_t SZ_ST = 20971520;   // B*5*IN bf16 bytes
  const size_t SZ_WL = 2097152;    // H*IN bf16 bytes
  const size_t SZ_W  = 8388608;    // H*H bf16 bytes
  const size_t SZ_WM = 131072;     // 32*H bf16 bytes

  char* ws = (char*)d_ws;
  bf16* x   = (bf16*)(ws);                       // [B,H]
  char* R   = ws + SZ_X;
  // phase 1 (freed after lif_kernel):
  bf16* sh  = (bf16*)(R);
  bf16* sl  = (bf16*)(R + SZ_ST);
  bf16* wlh = (bf16*)(R + 2 * SZ_ST);
  bf16* wll = (bf16*)(R + 2 * SZ_ST + SZ_WL);
  // phase 2 (aliases phase 1; written after lif_kernel completes):
  bf16* w11b = (bf16*)(R);
  bf16* w12b = (bf16*)(R + SZ_W);
  bf16* w21b = (bf16*)(R + 2 * SZ_W);
  bf16* w22b = (bf16*)(R + 3 * SZ_W);
  bf16* wmb  = (bf16*)(R + 4 * SZ_W);
  bf16* wlsb = (bf16*)(R + 4 * SZ_W + SZ_WM);
  bf16* h1   = (bf16*)(R + 4 * SZ_W + 2 * SZ_WM);
  bf16* h12  = (bf16*)(R + 4 * SZ_W + 2 * SZ_WM + SZ_X);

  // 1) split state + W_lif into hi/lo bf16
  split_kernel<<<(B * 5 * IN / 8 + 255) / 256, 256, 0, stream>>>(state, sh, sl, B * 5 * IN / 8);
  split_kernel<<<(H * IN / 8 + 255) / 256, 256, 0, stream>>>(W_lif, wlh, wll, H * IN / 8);

  // 2) fused fc-GEMM (split) + LIF -> x (bf16)
  lif_kernel<<<(B / 128) * (H / 128), 512, 0, stream>>>(sh, sl, wlh, wll, b_lif, x);

  // 3) convert MLP weights to bf16 (overwrites phase-1 region)
  cvt_kernel<<<(H * H / 8 + 255) / 256, 256, 0, stream>>>(W11, w11b, H * H / 8);
  cvt_kernel<<<(H * H / 8 + 255) / 256, 256, 0, stream>>>(W12, w12b, H * H / 8);
  cvt_kernel<<<(H * H / 8 + 255) / 256, 256, 0, stream>>>(W21, w21b, H * H / 8);
  cvt_kernel<<<(H * H / 8 + 255) / 256, 256, 0, stream>>>(W22, w22b, H * H / 8);
  cvt_kernel<<<(32 * H / 8 + 255) / 256, 256, 0, stream>>>(Wm, wmb, 32 * H / 8);
  cvt_kernel<<<(32 * H / 8 + 255) / 256, 256, 0, stream>>>(Wls, wlsb, 32 * H / 8);

  // 4) MLP trunk
  const int g = (B / 128) * (H / 128);
  gemm_relu_kernel<<<g, 256, 0, stream>>>(x,  w11b, b11, h1,  B, H, H);
  gemm_relu_kernel<<<g, 256, 0, stream>>>(h1, w12b, b12, h12, B, H, H);
  gemm_relu_kernel<<<g, 256, 0, stream>>>(x,  w21b, b21, h1,  B, H, H);   // h2
  gemm_relu_kernel<<<g, 256, 0, stream>>>(h1, w22b, b22, x,   B, H, H);   // h22

  // 5) heads -> d_out = [mean | log_std] fp32
  head_kernel<<<B / 64, 256, 0, stream>>>(h12, x, wmb, bm, wlsb, bls, out, B, H);
}

// Round 3
// 359.887 us; speedup vs baseline: 1.2810x; 1.2810x over previous
//
#include <hip/hip_runtime.h>
#include <hip/hip_bf16.h>

// GaussianPolicy: SNN-LIF frontend + 2-branch MLP heads.
// B=4096, IN=512, H=2048, A=32. fp32 in/out; fp16 MFMA compute internally
// (fp16's 11 mantissa bits keep LIF spike flips negligible -> no hi/lo split).

typedef _Float16 f16;
using f32x4 = __attribute__((ext_vector_type(4))) float;
using f16x8 = __attribute__((ext_vector_type(8))) f16;   // 8 fp16 = 4 VGPRs

#define MFMA16(a, b, c) __builtin_amdgcn_mfma_f32_16x16x32_f16((a), (b), (c), 0, 0, 0)

__device__ __forceinline__ void gload16(const void* g, void* l) {
  // async global->LDS, 16B/lane; LDS dest must be wave-uniform base + lane*16
  __builtin_amdgcn_global_load_lds(
      (const __attribute__((address_space(1))) unsigned int*)g,
      (__attribute__((address_space(3))) unsigned int*)l, 16, 0, 0);
}

// ---------------------------------------------------------------------------
// fp32 -> fp16 convert, 8 elems/thread
// ---------------------------------------------------------------------------
__global__ __launch_bounds__(256) void cvt_kernel(
    const float* __restrict__ src, f16* __restrict__ dst, int n8)
{
  int i = blockIdx.x * 256 + threadIdx.x;
  if (i >= n8) return;
  const float4* s4 = (const float4*)src;
  float4 a = s4[(size_t)i * 2], b = s4[(size_t)i * 2 + 1];
  f16x8 d;
  d[0] = (f16)a.x; d[1] = (f16)a.y; d[2] = (f16)a.z; d[3] = (f16)a.w;
  d[4] = (f16)b.x; d[5] = (f16)b.y; d[6] = (f16)b.z; d[7] = (f16)b.w;
  *(f16x8*)(dst + (size_t)i * 8) = d;
}

// ---------------------------------------------------------------------------
// LIF kernel: fc[b,s,h] = state_s @ W_lif^T (fp16), 15-step LIF, x = mean.
// Tile 64(M) x 128(N), 4 waves (2x2), wave 32x64; 5 slice accumulators.
// K=512, BK=32: W tile staged once per K-step, reused by all 5 slices.
// LDS 56 KB -> 2 blocks/CU.
// ---------------------------------------------------------------------------
__global__ __launch_bounds__(256) void lif_kernel(
    const f16* __restrict__ S,    // [4096, 5, 512] fp16
    const f16* __restrict__ W,    // [2048, 512] fp16
    const float* __restrict__ bl, // [2048] fp32
    f16* __restrict__ X)          // [4096, 2048] fp16
{
  const int K = 512, N = 2048;
  __shared__ alignas(16) f16 As[2][5][64 * 32];
  __shared__ alignas(16) f16 Bs[2][128 * 32];

  const int tid = threadIdx.x, wid = tid >> 6, lane = tid & 63;
  // bijective XCD swizzle (nwg=1024, %8==0), then col-major (bm fastest)
  const int nwg = 1024, q = nwg / 8;
  const int wg = (blockIdx.x % 8) * q + blockIdx.x / 8;
  const int bm = wg % 64, bn = wg / 64;          // nbm=64, nbn=16
  const int b0 = bm * 64, h0 = bn * 128;
  const int wr = (wid >> 1) * 32, wc = (wid & 1) * 64;
  const int srow = tid >> 2, skol = (tid & 3) * 8;
  const int kb = (lane >> 4) * 8, fr = lane & 15, fq = lane >> 4;

  f32x4 acc[5][2][4] = {};

  auto STAGE = [&](int p, int k0) {
#pragma unroll
    for (int s = 0; s < 5; ++s)
      gload16(S + ((size_t)(b0 + srow) * 5 + s) * K + k0 + skol, &As[p][s][tid * 8]);
#pragma unroll
    for (int r = 0; r < 2; ++r)
      gload16(W + (size_t)(h0 + r * 64 + srow) * K + k0 + skol, &Bs[p][r * 2048 + tid * 8]);
  };

  STAGE(0, 0);
  __syncthreads();
  int cur = 0;
  for (int kt = 0; kt < 16; ++kt) {
    if (kt + 1 < 16) STAGE(cur ^ 1, (kt + 1) * 32);
    f16x8 bf[4];
#pragma unroll
    for (int n = 0; n < 4; ++n)
      bf[n] = *(const f16x8*)&Bs[cur][(wc + n * 16 + fr) * 32 + kb];
#pragma unroll
    for (int s = 0; s < 5; ++s) {
      f16x8 af[2];
#pragma unroll
      for (int m = 0; m < 2; ++m)
        af[m] = *(const f16x8*)&As[cur][s][(wr + m * 16 + fr) * 32 + kb];
#pragma unroll
      for (int m = 0; m < 2; ++m)
#pragma unroll
        for (int n = 0; n < 4; ++n)
          acc[s][m][n] = MFMA16(af[m], bf[n], acc[s][m][n]);
    }
    __syncthreads();
    cur ^= 1;
  }

  // LIF epilogue: 5 slices x3 reps; x = spike count / 15
#pragma unroll
  for (int m = 0; m < 2; ++m) {
#pragma unroll
    for (int n = 0; n < 4; ++n) {
      const int col = h0 + wc + n * 16 + fr;
      const float bv = bl[col];
#pragma unroll
      for (int r = 0; r < 4; ++r) {
        const int row = b0 + wr + m * 16 + fq * 4 + r;
        float mem = 0.f, spk = 0.f, cnt = 0.f;
#pragma unroll
        for (int s = 0; s < 5; ++s) {
          const float fc = acc[s][m][n][r] + bv;
#pragma unroll
          for (int j = 0; j < 3; ++j) {
            mem = mem * 0.2f * (1.f - spk) + fc;   // DECAY=0.2
            spk = (mem > 0.2f) ? 1.f : 0.f;        // THRESH=0.2
            cnt += spk;
          }
        }
        X[(size_t)row * N + col] = (f16)(cnt / 15.0f);
      }
    }
  }
}

// ---------------------------------------------------------------------------
// Trunk GEMM: C = relu(A @ W^T + bias), fp16 in/out, fp32 bias/accum.
// Two column-halves may use different A/W/bias/C (layer-1 fusion).
// 128x128 tile, BK=32, 4 waves (2x2), wave 64x64 = 4x4 MFMA frags.
// ---------------------------------------------------------------------------
__global__ __launch_bounds__(256) void trunk_kernel(
    const f16* __restrict__ A0, const f16* __restrict__ A1, int lda,
    const f16* __restrict__ W0, const f16* __restrict__ W1,
    const float* __restrict__ bb0, const float* __restrict__ bb1,
    f16* __restrict__ C0, f16* __restrict__ C1, int ldc,
    int nbm, int nbn_total, int nbn_half, int K)
{
  __shared__ alignas(16) f16 As[2][128 * 32];
  __shared__ alignas(16) f16 Bs[2][128 * 32];

  const int tid = threadIdx.x, wid = tid >> 6, lane = tid & 63;
  const int nwg = nbm * nbn_total, q = nwg / 8;
  const int wg = (blockIdx.x % 8) * q + blockIdx.x / 8;
  const int bmi = wg % nbm, t = wg / nbm;
  const int half = (t >= nbn_half);
  const f16* A = half ? A1 : A0;
  const f16* W = half ? W1 : W0;
  const float* bias = half ? bb1 : bb0;
  f16* C = half ? C1 : C0;
  const int bm0 = bmi * 128;
  const int bn0 = (half ? t - nbn_half : t) * 128;

  const int wr = (wid >> 1) * 64, wc = (wid & 1) * 64;
  const int srow = tid >> 2, skol = (tid & 3) * 8;
  const int kb = (lane >> 4) * 8, fr = lane & 15, fq = lane >> 4;

  f32x4 acc[4][4] = {};

  auto STAGE = [&](int p, int k0) {
    gload16(A + (size_t)(bm0 + srow) * lda + k0 + skol,      &As[p][tid * 8]);
    gload16(A + (size_t)(bm0 + 64 + srow) * lda + k0 + skol, &As[p][2048 + tid * 8]);
    gload16(W + (size_t)(bn0 + srow) * K + k0 + skol,        &Bs[p][tid * 8]);
    gload16(W + (size_t)(bn0 + 64 + srow) * K + k0 + skol,   &Bs[p][2048 + tid * 8]);
  };

  STAGE(0, 0);
  __syncthreads();
  int cur = 0;
  const int NT = K / 32;
  for (int kt = 0; kt < NT; ++kt) {
    if (kt + 1 < NT) STAGE(cur ^ 1, (kt + 1) * 32);
    f16x8 af[4], bf[4];
#pragma unroll
    for (int m = 0; m < 4; ++m)
      af[m] = *(const f16x8*)&As[cur][(wr + m * 16 + fr) * 32 + kb];
#pragma unroll
    for (int n = 0; n < 4; ++n)
      bf[n] = *(const f16x8*)&Bs[cur][(wc + n * 16 + fr) * 32 + kb];
#pragma unroll
    for (int m = 0; m < 4; ++m)
#pragma unroll
      for (int n = 0; n < 4; ++n)
        acc[m][n] = MFMA16(af[m], bf[n], acc[m][n]);
    __syncthreads();
    cur ^= 1;
  }

#pragma unroll
  for (int n = 0; n < 4; ++n) {
    const int col = bn0 + wc + n * 16 + fr;
    const float bv = bias[col];
#pragma unroll
    for (int m = 0; m < 4; ++m) {
      const int row0 = bm0 + wr + m * 16 + fq * 4;
#pragma unroll
      for (int r = 0; r < 4; ++r) {
        float v = fmaxf(acc[m][n][r] + bv, 0.f);
        C[(size_t)(row0 + r) * ldc + col] = (f16)v;
      }
    }
  }
}

// ---------------------------------------------------------------------------
// Heads: mean = h12@Wm^T + bm ; log_std = clip(h22@Wls^T + bls, -20, 2). fp32 out.
// ---------------------------------------------------------------------------
__global__ __launch_bounds__(256) void head_kernel(
    const f16* __restrict__ H1, const f16* __restrict__ H2,
    const f16* __restrict__ Wm, const float* __restrict__ bm,
    const f16* __restrict__ Wls, const float* __restrict__ bls,
    float* __restrict__ OUT, int M, int K)
{
  const int tid = threadIdx.x, wid = tid >> 6, lane = tid & 63;
  const int m0 = blockIdx.x * 64 + wid * 16;
  const int kb = (lane >> 4) * 8, fr = lane & 15, fq = lane >> 4;

  f32x4 a1[2] = {}, a2[2] = {};
  for (int k0 = 0; k0 < K; k0 += 32) {
    f16x8 f1 = *(const f16x8*)&H1[(size_t)(m0 + fr) * K + k0 + kb];
    f16x8 f2 = *(const f16x8*)&H2[(size_t)(m0 + fr) * K + k0 + kb];
#pragma unroll
    for (int n = 0; n < 2; ++n) {
      f16x8 wm = *(const f16x8*)&Wm[(size_t)(n * 16 + fr) * K + k0 + kb];
      f16x8 wl = *(const f16x8*)&Wls[(size_t)(n * 16 + fr) * K + k0 + kb];
      a1[n] = MFMA16(f1, wm, a1[n]);
      a2[n] = MFMA16(f2, wl, a2[n]);
    }
  }

#pragma unroll
  for (int n = 0; n < 2; ++n) {
    const int col = n * 16 + fr;
    const float bvm = bm[col];
    const float bvl = bls[col];
#pragma unroll
    for (int r = 0; r < 4; ++r) {
      const int row = m0 + fq * 4 + r;
      OUT[(size_t)row * 32 + col] = a1[n][r] + bvm;
      float lv = a2[n][r] + bvl;
      OUT[(size_t)M * 32 + (size_t)row * 32 + col] = fminf(fmaxf(lv, -20.f), 2.f);
    }
  }
}

// ---------------------------------------------------------------------------
extern "C" void kernel_launch(void* const* d_in, const int* in_sizes, int n_in,
                              void* d_out, int out_size, void* d_ws, size_t ws_size,
                              hipStream_t stream) {
  const float* state = (const float*)d_in[0];
  const float* W_lif = (const float*)d_in[1];
  const float* b_lif = (const float*)d_in[2];
  const float* W11   = (const float*)d_in[3];
  const float* b11   = (const float*)d_in[4];
  const float* W12   = (const float*)d_in[5];
  const float* b12   = (const float*)d_in[6];
  const float* W21   = (const float*)d_in[7];
  const float* b21   = (const float*)d_in[8];
  const float* W22   = (const float*)d_in[9];
  const float* b22   = (const float*)d_in[10];
  const float* Wm    = (const float*)d_in[11];
  const float* bm    = (const float*)d_in[12];
  const float* Wls   = (const float*)d_in[13];
  const float* bls   = (const float*)d_in[14];
  float* out = (float*)d_out;

  const int B = 4096, IN = 512, H = 2048;
  char* ws = (char*)d_ws;
  // layout (bytes). Peak 75.6 MB.
  f16* x    = (f16*)(ws);                      // [4096,2048] -> h12 after trunk2a
  f16* h1   = (f16*)(ws + 16777216);           // [4096,2048] -> h22 after trunk2b
  f16* h2   = (f16*)(ws + 33554432);           // [4096,2048]
  f16* s16  = (f16*)(ws + 50331648);           // [4096,5,512]  (dead after lif)
  f16* wl16 = (f16*)(ws + 71303168);           // [2048,512]    (dead after lif)
  f16* w11h = (f16*)(ws + 50331648);           // [2048,2048] over s16, after lif
  f16* w21h = (f16*)(ws + 58720256);           // [2048,2048]
  f16* w12h = (f16*)(ws + 67108864);           // [2048,2048] (peak 75.6MB)
  f16* w22h = (f16*)(ws + 67108864);           // reuses w12h slot after trunk2a
  f16* wmh  = (f16*)(ws + 50331648);           // [32,2048] over w11h, after trunk1
  f16* wlsh = (f16*)(ws + 50462720);           // [32,2048]
  f16* h12  = x;                               // written by trunk2a
  f16* h22  = h1;                              // written by trunk2b

  // 1) converts needed by LIF
  cvt_kernel<<<(B * 5 * IN / 8) / 256, 256, 0, stream>>>(state, s16, B * 5 * IN / 8);
  cvt_kernel<<<(H * IN / 8) / 256, 256, 0, stream>>>(W_lif, wl16, H * IN / 8);

  // 2) fused fc-GEMM + LIF -> x
  lif_kernel<<<1024, 256, 0, stream>>>(s16, wl16, b_lif, x);

  // 3) layer-1 weights (overwrite s16 region), fused layer-1 GEMM
  cvt_kernel<<<(H * H / 8) / 256, 256, 0, stream>>>(W11, w11h, H * H / 8);
  cvt_kernel<<<(H * H / 8) / 256, 256, 0, stream>>>(W21, w21h, H * H / 8);
  trunk_kernel<<<1024, 256, 0, stream>>>(x, x, H, w11h, w21h, b11, b21,
                                         h1, h2, H, 32, 32, 16, H);

  // 4) layer-2 (two dispatches so w22 reuses w12's slot)
  cvt_kernel<<<(H * H / 8) / 256, 256, 0, stream>>>(W12, w12h, H * H / 8);
  trunk_kernel<<<512, 256, 0, stream>>>(h1, h1, H, w12h, w12h, b12, b12,
                                        h12, h12, H, 32, 16, 16, H);
  cvt_kernel<<<(H * H / 8) / 256, 256, 0, stream>>>(W22, w22h, H * H / 8);
  trunk_kernel<<<512, 256, 0, stream>>>(h2, h2, H, w22h, w22h, b22, b22,
                                        h22, h22, H, 32, 16, 16, H);

  // 5) heads
  cvt_kernel<<<(32 * H / 8) / 256, 256, 0, stream>>>(Wm, wmh, 32 * H / 8);
  cvt_kernel<<<(32 * H / 8) / 256, 256, 0, stream>>>(Wls, wlsh, 32 * H / 8);
  head_kernel<<<B / 64, 256, 0, stream>>>(h12, h22, wmh, bm, wlsh, bls, out, B, H);
}